// Round 4
// baseline (154.992 us; speedup 1.0000x reference)
//
#include <hip/hip_runtime.h>
#include <hip/hip_bf16.h>

typedef unsigned short u16;
typedef unsigned int u32;
typedef __attribute__((ext_vector_type(8))) short bf16x8;
typedef __attribute__((ext_vector_type(4))) float f32x4;
typedef __attribute__((ext_vector_type(4))) u32 u32x4;

typedef __attribute__((address_space(1))) const void gvoid;
typedef __attribute__((address_space(3))) void svoid;

__device__ __forceinline__ void gload16(const void* g, void* l) {
  __builtin_amdgcn_global_load_lds((gvoid*)g, (svoid*)l, 16, 0, 0);
}

__device__ __forceinline__ u16 f2bf(float x){
  union { float f; unsigned u; } v; v.f = x;
  unsigned r = v.u + 0x7fffu + ((v.u >> 16) & 1u);
  return (u16)(r >> 16);
}
// pack two f32 into two bf16 (TRUNCATED) in one v_perm_b32
__device__ __forceinline__ u32 pack_trunc(float a, float b){
  union { float f; u32 u; } ua, ub; ua.f = a; ub.f = b;
  return __builtin_amdgcn_perm(ub.u, ua.u, 0x07060302u);
}
__device__ __forceinline__ float fast_tanh(float x){
  x = fminf(fmaxf(x, -12.f), 12.f);
  float e = __expf(2.f * x);
  return (e - 1.f) / (e + 1.f);
}
__device__ __forceinline__ float fast_sig(float x){
  return 1.f / (1.f + __expf(-x));
}

// ---------------- prep: bf16 conversions + concat buffers (4 elems/thread) ----------------
__global__ __launch_bounds__(256) void prep_kernel(
    const float* __restrict__ Wfeat, const float* __restrict__ Whid,
    const float* __restrict__ Wih,   const float* __restrict__ Whh,
    const float* __restrict__ onehot,const float* __restrict__ prevh,
    const float* __restrict__ bih,   const float* __restrict__ bhh,
    u16* __restrict__ wfeat_b, u16* __restrict__ whid_b,
    u16* __restrict__ wcat, u16* __restrict__ xh, float* __restrict__ biascat)
{
  int idx = (blockIdx.x * 256 + threadIdx.x) * 4;
  const float* src;
  u16* dst;
  if (idx < 262144) { src = Wfeat + idx; dst = wfeat_b + idx; }
  else if ((idx -= 262144) < 262144) { src = Whid + idx; dst = whid_b + idx; }
  else if ((idx -= 262144) < 2097152) {
    int r = idx >> 10, k = idx & 1023; src = Wih + idx; dst = wcat + r*1536 + k;
  }
  else if ((idx -= 2097152) < 1048576) {
    int r = idx >> 9, k = idx & 511; src = Whh + idx; dst = wcat + r*1536 + 1024 + k;
  }
  else if ((idx -= 1048576) < 131072) {
    int b = idx >> 9, e = idx & 511; src = onehot + idx; dst = xh + b*1536 + 512 + e;
  }
  else if ((idx -= 131072) < 131072) {
    int b = idx >> 9, h = idx & 511; src = prevh + idx; dst = xh + b*1536 + 1024 + h;
  }
  else {
    idx -= 131072;
    if (idx < 2048) {
      float4 a = *(const float4*)(bih + idx);
      float4 b = *(const float4*)(bhh + idx);
      float4 c = { a.x + b.x, a.y + b.y, a.z + b.z, a.w + b.w };
      *(float4*)(biascat + idx) = c;
    }
    return;
  }
  float4 v = *(const float4*)src;
  ushort4 u;
  u.x = f2bf(v.x); u.y = f2bf(v.y); u.z = f2bf(v.z); u.w = f2bf(v.w);
  *(ushort4*)dst = u;
}

// ---------------- split-K partial GEMM: P[z] = A(bf16,[M][lda]) @ W(bf16,[N][ldw])^T ------
// tile 128x128, 4 waves, 16x16x32 MFMA. blockIdx.z = K-split index.
__global__ __launch_bounds__(256) void gemm_btk(
    const u16* __restrict__ Ab, int lda,
    const u16* __restrict__ Wb, int ldw,
    int ksteps, int pstride,
    float* __restrict__ P, int ldc)
{
  __shared__ u16 sA[128][40];
  __shared__ u16 sW[128][40];
  const int tid = threadIdx.x;
  const int lane = tid & 63, wave = tid >> 6;
  const int wr = wave >> 1, wc = wave & 1;
  const int lr = lane & 15, kg = lane >> 4;
  const int m0 = blockIdx.x * 128, n0 = blockIdx.y * 128;
  const int kbase = blockIdx.z * ksteps * 32;
  P += (size_t)blockIdx.z * pstride;
  const int sr = tid >> 1, sh = tid & 1;

  const f32x4 zero = {0.f, 0.f, 0.f, 0.f};
  f32x4 acc[4][4];
  #pragma unroll
  for (int i = 0; i < 4; ++i)
    #pragma unroll
    for (int j = 0; j < 4; ++j)
      acc[i][j] = zero;

  for (int ks = 0; ks < ksteps; ++ks) {
    const int kt = kbase + ks * 32;
    __syncthreads();
    {
      const u16* ap = Ab + (size_t)(m0 + sr) * lda + kt + sh * 16;
      *(bf16x8*)&sA[sr][sh*16]     = *(const bf16x8*)ap;
      *(bf16x8*)&sA[sr][sh*16 + 8] = *(const bf16x8*)(ap + 8);
      const u16* wp = Wb + (size_t)(n0 + sr) * ldw + kt + sh * 16;
      *(bf16x8*)&sW[sr][sh*16]     = *(const bf16x8*)wp;
      *(bf16x8*)&sW[sr][sh*16 + 8] = *(const bf16x8*)(wp + 8);
    }
    __syncthreads();
    bf16x8 af[4], wf[4];
    #pragma unroll
    for (int mi = 0; mi < 4; ++mi) af[mi] = *(const bf16x8*)&sA[wr*64 + mi*16 + lr][kg*8];
    #pragma unroll
    for (int ni = 0; ni < 4; ++ni) wf[ni] = *(const bf16x8*)&sW[wc*64 + ni*16 + lr][kg*8];
    #pragma unroll
    for (int mi = 0; mi < 4; ++mi)
      #pragma unroll
      for (int ni = 0; ni < 4; ++ni)
        acc[mi][ni] = __builtin_amdgcn_mfma_f32_16x16x32_bf16(af[mi], wf[ni], acc[mi][ni], 0, 0, 0);
  }

  #pragma unroll
  for (int ni = 0; ni < 4; ++ni) {
    const int col = n0 + wc*64 + ni*16 + lr;
    #pragma unroll
    for (int mi = 0; mi < 4; ++mi) {
      const int row = m0 + wr*64 + mi*16 + kg*4;
      #pragma unroll
      for (int rr = 0; rr < 4; ++rr)
        P[(size_t)(row + rr) * ldc + col] = acc[mi][ni][rr];
    }
  }
}

// ---------------- energies: m97-structure GEMM, A = f32 (in-reg trunc convert) ----------
// A = batch_H f32 [65536][512], W = wfeat_b bf16 [512][512].
// 256 threads, 4 waves (2x2), tile 128x128, BK=32, grid (512,4).
// sA: reg-staged f32->bf16 via v_perm, XOR-swizzled 16B chunks (2-way banks).
// sW: global_load_lds x2/lane, linear (m97 layout).
// hidden_proj = sum of 4 split-K partials + b_hid folded into epilogue.
__global__ __launch_bounds__(256) void energies_gemm(
    const float* __restrict__ A, const u16* __restrict__ Wb,
    const float* __restrict__ hpp, const float* __restrict__ bhid,
    const float* __restrict__ wsc, float* __restrict__ epart)
{
  __shared__ u16 sA[128 * 32];   // 8 KB
  __shared__ u16 sW[128 * 32];   // 8 KB
  const int tid = threadIdx.x;
  const int lane = tid & 63, wv = tid >> 6;
  const int wr = wv >> 1, wc = wv & 1;
  const int lr = lane & 15, kg = lane >> 4;
  const int m0 = blockIdx.x * 128, n0 = blockIdx.y * 128;
  const int b = m0 >> 8;

  // A staging: thread -> row = tid>>1, 16-f32 half = tid&1; swizzle s(r) = (r>>1)&3
  const int arow = tid >> 1, ahalf = tid & 1;
  const float* gA = A + (size_t)(m0 + arow) * 512 + ahalf * 16;
  const int s_r = (arow >> 1) & 3;
  u32* lA0 = (u32*)(sA + arow * 32 + (((ahalf*2 + 0) ^ s_r) * 8));
  u32* lA1 = (u32*)(sA + arow * 32 + (((ahalf*2 + 1) ^ s_r) * 8));

  // W staging: wave chunk = 2KB (32 rows); lane l -> row wv*32 + g*16 + (l>>2), chunk l&3
  const u16* gW0 = Wb + (size_t)(n0 + wv*32 + (lane >> 2)) * 512 + (lane & 3) * 8;
  const u16* gW1 = gW0 + 16 * 512;
  u16* lW0 = sW + wv * 1024;
  u16* lW1 = lW0 + 512;

  const f32x4 zero = {0.f, 0.f, 0.f, 0.f};
  f32x4 acc[4][4];
  #pragma unroll
  for (int i = 0; i < 4; ++i)
    #pragma unroll
    for (int j = 0; j < 4; ++j)
      acc[i][j] = zero;

  for (int kt = 0; kt < 512; kt += 32) {
    __syncthreads();
    gload16(gW0 + kt, lW0);
    gload16(gW1 + kt, lW1);
    float4 v0 = *(const float4*)(gA + kt);
    float4 v1 = *(const float4*)(gA + kt + 4);
    float4 v2 = *(const float4*)(gA + kt + 8);
    float4 v3 = *(const float4*)(gA + kt + 12);
    u32x4 c0, c1;
    c0[0] = pack_trunc(v0.x, v0.y); c0[1] = pack_trunc(v0.z, v0.w);
    c0[2] = pack_trunc(v1.x, v1.y); c0[3] = pack_trunc(v1.z, v1.w);
    c1[0] = pack_trunc(v2.x, v2.y); c1[1] = pack_trunc(v2.z, v2.w);
    c1[2] = pack_trunc(v3.x, v3.y); c1[3] = pack_trunc(v3.z, v3.w);
    *(u32x4*)lA0 = c0;
    *(u32x4*)lA1 = c1;
    __syncthreads();
    bf16x8 af[4], wf[4];
    #pragma unroll
    for (int mi = 0; mi < 4; ++mi) {
      const int row = wr*64 + mi*16 + lr;
      af[mi] = *(const bf16x8*)&sA[row * 32 + ((kg ^ ((row >> 1) & 3)) * 8)];
    }
    #pragma unroll
    for (int ni = 0; ni < 4; ++ni)
      wf[ni] = *(const bf16x8*)&sW[(wc*64 + ni*16 + lr) * 32 + kg*8];
    #pragma unroll
    for (int mi = 0; mi < 4; ++mi)
      #pragma unroll
      for (int ni = 0; ni < 4; ++ni)
        acc[mi][ni] = __builtin_amdgcn_mfma_f32_16x16x32_bf16(af[mi], wf[ni], acc[mi][ni], 0, 0, 0);
  }

  // epilogue: hidden_proj reduce + bias, tanh, w_score, 16-lane reduce
  float hpv[4], wsv[4];
  #pragma unroll
  for (int ni = 0; ni < 4; ++ni) {
    const int col = n0 + wc*64 + ni*16 + lr;
    float h = bhid[col];
    #pragma unroll
    for (int z = 0; z < 4; ++z) h += hpp[z * 131072 + b * 512 + col];
    hpv[ni] = h;
    wsv[ni] = wsc[col];
  }
  const int p = blockIdx.y * 2 + wc;
  #pragma unroll
  for (int mi = 0; mi < 4; ++mi) {
    #pragma unroll
    for (int rr = 0; rr < 4; ++rr) {
      float s = 0.f;
      #pragma unroll
      for (int ni = 0; ni < 4; ++ni)
        s += fast_tanh(acc[mi][ni][rr] + hpv[ni]) * wsv[ni];
      s += __shfl_xor(s, 1, 64);
      s += __shfl_xor(s, 2, 64);
      s += __shfl_xor(s, 4, 64);
      s += __shfl_xor(s, 8, 64);
      if (lr == 0)
        epart[p * 65536 + m0 + wr*64 + mi*16 + kg*4 + rr] = s;
    }
  }
}

// ---------------- fused softmax + context (per batch element) ----------------
__global__ __launch_bounds__(256) void softctx_k(
    const float* __restrict__ epart, const float* __restrict__ H,
    float* __restrict__ alpha, u16* __restrict__ xh)
{
  const int bb = blockIdx.x, t = threadIdx.x;
  float e = 0.f;
  #pragma unroll
  for (int p = 0; p < 8; ++p) e += epart[p * 65536 + bb * 256 + t];
  float mx = e;
  #pragma unroll
  for (int o = 32; o >= 1; o >>= 1) mx = fmaxf(mx, __shfl_xor(mx, o, 64));
  __shared__ float sm[4], ss[4];
  if ((t & 63) == 0) sm[t >> 6] = mx;
  __syncthreads();
  mx = fmaxf(fmaxf(sm[0], sm[1]), fmaxf(sm[2], sm[3]));
  float ex = __expf(e - mx);
  float sum = ex;
  #pragma unroll
  for (int o = 32; o >= 1; o >>= 1) sum += __shfl_xor(sum, o, 64);
  if ((t & 63) == 0) ss[t >> 6] = sum;
  __syncthreads();
  sum = ss[0] + ss[1] + ss[2] + ss[3];
  const float av = ex / sum;
  alpha[bb * 256 + t] = av;
  __shared__ float sal[256];
  sal[t] = av;
  __syncthreads();
  const int q = t >> 6, c = t & 63;
  float a[8];
  #pragma unroll
  for (int j = 0; j < 8; ++j) a[j] = 0.f;
  const float* p = H + (size_t)bb * 131072 + c * 8;
  for (int s = q * 64; s < q * 64 + 64; ++s) {
    float4 v0 = *(const float4*)(p + (size_t)s * 512);
    float4 v1 = *(const float4*)(p + (size_t)s * 512 + 4);
    const float al = sal[s];
    a[0] = fmaf(al, v0.x, a[0]); a[1] = fmaf(al, v0.y, a[1]);
    a[2] = fmaf(al, v0.z, a[2]); a[3] = fmaf(al, v0.w, a[3]);
    a[4] = fmaf(al, v1.x, a[4]); a[5] = fmaf(al, v1.y, a[5]);
    a[6] = fmaf(al, v1.z, a[6]); a[7] = fmaf(al, v1.w, a[7]);
  }
  __shared__ float red[256][8];
  #pragma unroll
  for (int j = 0; j < 8; ++j) red[t][j] = a[j];
  __syncthreads();
  if (q == 0) {
    #pragma unroll
    for (int j = 0; j < 8; ++j) {
      float s = red[t][j] + red[t + 64][j] + red[t + 128][j] + red[t + 192][j];
      xh[bb * 1536 + c * 8 + j] = f2bf(s);
    }
  }
}

// ---------------- gates split-K reduce + bias + LSTM elementwise ----------------
__global__ __launch_bounds__(256) void lstm_reduce(
    const float* __restrict__ P, const float* __restrict__ biascat,
    const float* __restrict__ prev_c, float* __restrict__ out)
{
  const int idx = blockIdx.x * 256 + threadIdx.x;   // 0..131071
  const int b = idx >> 9, h = idx & 511;
  float gi = biascat[h], gf = biascat[512 + h], gg = biascat[1024 + h], go = biascat[1536 + h];
  #pragma unroll
  for (int z = 0; z < 4; ++z) {
    const float* q = P + (size_t)z * 524288 + (size_t)b * 2048;
    gi += q[h]; gf += q[512 + h]; gg += q[1024 + h]; go += q[1536 + h];
  }
  const float c = fast_sig(gf) * prev_c[idx] + fast_sig(gi) * fast_tanh(gg);
  out[idx] = fast_sig(go) * fast_tanh(c);   // h_new
  out[131072 + idx] = c;                     // c_new
}

extern "C" void kernel_launch(void* const* d_in, const int* in_sizes, int n_in,
                              void* d_out, int out_size, void* d_ws, size_t ws_size,
                              hipStream_t stream) {
  const float* prev_h  = (const float*)d_in[0];
  const float* prev_c  = (const float*)d_in[1];
  const float* batch_H = (const float*)d_in[2];
  const float* onehot  = (const float*)d_in[3];
  const float* W_feat  = (const float*)d_in[4];
  const float* W_hid   = (const float*)d_in[5];
  const float* b_hid   = (const float*)d_in[6];
  const float* w_score = (const float*)d_in[7];
  const float* W_ih    = (const float*)d_in[8];
  const float* W_hh    = (const float*)d_in[9];
  const float* b_ih    = (const float*)d_in[10];
  const float* b_hh    = (const float*)d_in[11];
  float* out = (float*)d_out;   // [h_new 131072 | c_new 131072 | alpha 65536]

  char* ws = (char*)d_ws;
  u16*   wfeat_b = (u16*)(ws);               //   524288 B
  u16*   whid_b  = (u16*)(ws + 524288);      //   524288 B
  u16*   wcat    = (u16*)(ws + 1048576);     //  6291456 B  [2048][1536] = [W_ih | W_hh]
  u16*   xh      = (u16*)(ws + 7340032);     //   786432 B  [256][1536] = [context|onehot|prev_h]
  float* biascat = (float*)(ws + 8126464);   //     8192 B
  float* hpp     = (float*)(ws + 8134656);   //  2097152 B  hidden partials [4][256][512]
  float* epart   = (float*)(ws + 10231808);  //  2097152 B  [8][65536]
  float* gpart   = (float*)(ws + 12328960);  //  8388608 B  gate partials [4][256][2048]
  // total 20717568 bytes

  float* alpha = out + 262144;

  prep_kernel<<<3842, 256, 0, stream>>>(W_feat, W_hid, W_ih, W_hh, onehot, prev_h,
                                        b_ih, b_hh, wfeat_b, whid_b, wcat, xh, biascat);
  // hidden_proj partials: prev_h @ W_hid^T  (split-K x4, bias folded into energies)
  gemm_btk<<<dim3(2, 4, 4), 256, 0, stream>>>(xh + 1024, 1536, whid_b, 512, 4, 131072, hpp, 512);
  // energies: fused feat_proj GEMM + hidden-reduce + tanh + w_score reduce (m97 structure)
  energies_gemm<<<dim3(512, 4), 256, 0, stream>>>(batch_H, wfeat_b, hpp, b_hid, w_score, epart);
  // softmax + context (writes alpha output and xh context slice)
  softctx_k<<<256, 256, 0, stream>>>(epart, batch_H, alpha, xh);
  // gates partials: [context|onehot|prev_h] @ [W_ih|W_hh]^T (split-K x4)
  gemm_btk<<<dim3(2, 16, 4), 256, 0, stream>>>(xh, 1536, wcat, 1536, 12, 524288, gpart, 2048);
  // reduce + bias + LSTM
  lstm_reduce<<<512, 256, 0, stream>>>(gpart, biascat, prev_c, out);
}

// Round 5
// 127.187 us; speedup vs baseline: 1.2186x; 1.2186x over previous
//
#include <hip/hip_runtime.h>
#include <hip/hip_bf16.h>

typedef unsigned short u16;
typedef unsigned int u32;
typedef __attribute__((ext_vector_type(8))) short bf16x8;
typedef __attribute__((ext_vector_type(4))) float f32x4;
typedef __attribute__((ext_vector_type(4))) u32 u32x4;

typedef __attribute__((address_space(1))) const void gvoid;
typedef __attribute__((address_space(3))) void svoid;

__device__ __forceinline__ void gload16(const void* g, void* l) {
  __builtin_amdgcn_global_load_lds((gvoid*)g, (svoid*)l, 16, 0, 0);
}

__device__ __forceinline__ u16 f2bf(float x){
  union { float f; unsigned u; } v; v.f = x;
  unsigned r = v.u + 0x7fffu + ((v.u >> 16) & 1u);
  return (u16)(r >> 16);
}
// pack two f32 into two bf16 (TRUNCATED) in one v_perm_b32
__device__ __forceinline__ u32 pack_trunc(float a, float b){
  union { float f; u32 u; } ua, ub; ua.f = a; ub.f = b;
  return __builtin_amdgcn_perm(ub.u, ua.u, 0x07060302u);
}
__device__ __forceinline__ float fast_tanh(float x){
  x = fminf(fmaxf(x, -12.f), 12.f);
  float e = __expf(2.f * x);
  return (e - 1.f) / (e + 1.f);
}
__device__ __forceinline__ float fast_sig(float x){
  return 1.f / (1.f + __expf(-x));
}

// ---------------- prep: bf16 conversions + concat buffers (4 elems/thread) ----------------
__global__ __launch_bounds__(256) void prep_kernel(
    const float* __restrict__ Wfeat, const float* __restrict__ Whid,
    const float* __restrict__ Wih,   const float* __restrict__ Whh,
    const float* __restrict__ onehot,const float* __restrict__ prevh,
    const float* __restrict__ bih,   const float* __restrict__ bhh,
    u16* __restrict__ wfeat_b, u16* __restrict__ whid_b,
    u16* __restrict__ wcat, u16* __restrict__ xh, float* __restrict__ biascat)
{
  int idx = (blockIdx.x * 256 + threadIdx.x) * 4;
  const float* src;
  u16* dst;
  if (idx < 262144) { src = Wfeat + idx; dst = wfeat_b + idx; }
  else if ((idx -= 262144) < 262144) { src = Whid + idx; dst = whid_b + idx; }
  else if ((idx -= 262144) < 2097152) {
    int r = idx >> 10, k = idx & 1023; src = Wih + idx; dst = wcat + r*1536 + k;
  }
  else if ((idx -= 2097152) < 1048576) {
    int r = idx >> 9, k = idx & 511; src = Whh + idx; dst = wcat + r*1536 + 1024 + k;
  }
  else if ((idx -= 1048576) < 131072) {
    int b = idx >> 9, e = idx & 511; src = onehot + idx; dst = xh + b*1536 + 512 + e;
  }
  else if ((idx -= 131072) < 131072) {
    int b = idx >> 9, h = idx & 511; src = prevh + idx; dst = xh + b*1536 + 1024 + h;
  }
  else {
    idx -= 131072;
    if (idx < 2048) {
      float4 a = *(const float4*)(bih + idx);
      float4 b = *(const float4*)(bhh + idx);
      float4 c = { a.x + b.x, a.y + b.y, a.z + b.z, a.w + b.w };
      *(float4*)(biascat + idx) = c;
    }
    return;
  }
  float4 v = *(const float4*)src;
  ushort4 u;
  u.x = f2bf(v.x); u.y = f2bf(v.y); u.z = f2bf(v.z); u.w = f2bf(v.w);
  *(ushort4*)dst = u;
}

// ---------------- split-K partial GEMM: P[z] = A(bf16,[M][lda]) @ W(bf16,[N][ldw])^T ------
// tile 128x128, 4 waves, 16x16x32 MFMA. blockIdx.z = K-split index.
__global__ __launch_bounds__(256) void gemm_btk(
    const u16* __restrict__ Ab, int lda,
    const u16* __restrict__ Wb, int ldw,
    int ksteps, int pstride,
    float* __restrict__ P, int ldc)
{
  __shared__ u16 sA[128][40];
  __shared__ u16 sW[128][40];
  const int tid = threadIdx.x;
  const int lane = tid & 63, wave = tid >> 6;
  const int wr = wave >> 1, wc = wave & 1;
  const int lr = lane & 15, kg = lane >> 4;
  const int m0 = blockIdx.x * 128, n0 = blockIdx.y * 128;
  const int kbase = blockIdx.z * ksteps * 32;
  P += (size_t)blockIdx.z * pstride;
  const int sr = tid >> 1, sh = tid & 1;

  const f32x4 zero = {0.f, 0.f, 0.f, 0.f};
  f32x4 acc[4][4];
  #pragma unroll
  for (int i = 0; i < 4; ++i)
    #pragma unroll
    for (int j = 0; j < 4; ++j)
      acc[i][j] = zero;

  for (int ks = 0; ks < ksteps; ++ks) {
    const int kt = kbase + ks * 32;
    __syncthreads();
    {
      const u16* ap = Ab + (size_t)(m0 + sr) * lda + kt + sh * 16;
      *(bf16x8*)&sA[sr][sh*16]     = *(const bf16x8*)ap;
      *(bf16x8*)&sA[sr][sh*16 + 8] = *(const bf16x8*)(ap + 8);
      const u16* wp = Wb + (size_t)(n0 + sr) * ldw + kt + sh * 16;
      *(bf16x8*)&sW[sr][sh*16]     = *(const bf16x8*)wp;
      *(bf16x8*)&sW[sr][sh*16 + 8] = *(const bf16x8*)(wp + 8);
    }
    __syncthreads();
    bf16x8 af[4], wf[4];
    #pragma unroll
    for (int mi = 0; mi < 4; ++mi) af[mi] = *(const bf16x8*)&sA[wr*64 + mi*16 + lr][kg*8];
    #pragma unroll
    for (int ni = 0; ni < 4; ++ni) wf[ni] = *(const bf16x8*)&sW[wc*64 + ni*16 + lr][kg*8];
    #pragma unroll
    for (int mi = 0; mi < 4; ++mi)
      #pragma unroll
      for (int ni = 0; ni < 4; ++ni)
        acc[mi][ni] = __builtin_amdgcn_mfma_f32_16x16x32_bf16(af[mi], wf[ni], acc[mi][ni], 0, 0, 0);
  }

  #pragma unroll
  for (int ni = 0; ni < 4; ++ni) {
    const int col = n0 + wc*64 + ni*16 + lr;
    #pragma unroll
    for (int mi = 0; mi < 4; ++mi) {
      const int row = m0 + wr*64 + mi*16 + kg*4;
      #pragma unroll
      for (int rr = 0; rr < 4; ++rr)
        P[(size_t)(row + rr) * ldc + col] = acc[mi][ni][rr];
    }
  }
}

// ---------------- energies: double-buffered pipelined GEMM, A = f32 (in-reg trunc) -------
// A = batch_H f32 [65536][512], W = wfeat_b bf16 [512][512].
// BM=128, BN=256, BK=32; 512 threads, 8 waves (2x4), per-wave 64x64; grid (512,2).
// Per K-step: issue next A (reg) + next W (global_load_lds, other buffer), compute
// current buffer (16 MFMA/wave), convert+ds_write next A, ONE barrier.
__global__ __launch_bounds__(512, 4) void energies_gemm(
    const float* __restrict__ A, const u16* __restrict__ Wb,
    const float* __restrict__ hpp, const float* __restrict__ bhid,
    const float* __restrict__ wsc, float* __restrict__ epart)
{
  __shared__ u16 sA[2][128 * 32];   // 2 x 8 KB
  __shared__ u16 sW[2][256 * 32];   // 2 x 16 KB
  const int tid = threadIdx.x;
  const int lane = tid & 63, wv = tid >> 6;
  const int wr = wv >> 2, wc = wv & 3;
  const int lr = lane & 15, kg = lane >> 4;
  const int m0 = blockIdx.x * 128, n0 = blockIdx.y * 256;
  const int b = m0 >> 8;

  // A staging: thread -> (row = tid>>2, 8-f32 chunk = tid&3); swizzled dest chunk
  const int arow = tid >> 2, achk = tid & 3;
  const float* gA = A + (size_t)(m0 + arow) * 512 + achk * 8;
  const int adst = arow * 32 + ((achk ^ ((arow >> 1) & 3)) * 8);

  // W staging: 2 x gload16/thread covering 256 rows x 32 cols, linear LDS
  const u16* gW0 = Wb + (size_t)(n0 + wv * 16 + (lane >> 2)) * 512 + (lane & 3) * 8;
  const u16* gW1 = gW0 + 128 * 512;
  const int wdst0 = wv * 1024;
  const int wdst1 = wdst0 + 4096;

  const f32x4 zero = {0.f, 0.f, 0.f, 0.f};
  f32x4 acc[4][4];
  #pragma unroll
  for (int i = 0; i < 4; ++i)
    #pragma unroll
    for (int j = 0; j < 4; ++j)
      acc[i][j] = zero;

  // prologue: tile 0 -> buffer 0
  float4 p0 = *(const float4*)(gA);
  float4 p1 = *(const float4*)(gA + 4);
  gload16(gW0, &sW[0][wdst0]);
  gload16(gW1, &sW[0][wdst1]);
  {
    u32x4 c;
    c[0] = pack_trunc(p0.x, p0.y); c[1] = pack_trunc(p0.z, p0.w);
    c[2] = pack_trunc(p1.x, p1.y); c[3] = pack_trunc(p1.z, p1.w);
    *(u32x4*)&sA[0][adst] = c;
  }
  __syncthreads();

  for (int t = 0; t < 16; ++t) {
    const int cur = t & 1, nxt = cur ^ 1;
    if (t < 15) {   // issue next-tile loads early (T14)
      const int kt = (t + 1) * 32;
      p0 = *(const float4*)(gA + kt);
      p1 = *(const float4*)(gA + kt + 4);
      gload16(gW0 + kt, &sW[nxt][wdst0]);
      gload16(gW1 + kt, &sW[nxt][wdst1]);
    }
    bf16x8 af[4], wf[4];
    #pragma unroll
    for (int mi = 0; mi < 4; ++mi) {
      const int row = wr*64 + mi*16 + lr;
      af[mi] = *(const bf16x8*)&sA[cur][row * 32 + ((kg ^ ((row >> 1) & 3)) * 8)];
    }
    #pragma unroll
    for (int ni = 0; ni < 4; ++ni)
      wf[ni] = *(const bf16x8*)&sW[cur][(wc*64 + ni*16 + lr) * 32 + kg*8];
    #pragma unroll
    for (int mi = 0; mi < 4; ++mi)
      #pragma unroll
      for (int ni = 0; ni < 4; ++ni)
        acc[mi][ni] = __builtin_amdgcn_mfma_f32_16x16x32_bf16(af[mi], wf[ni], acc[mi][ni], 0, 0, 0);
    if (t < 15) {   // convert + write next A tile (compiler inserts vmcnt wait)
      u32x4 c;
      c[0] = pack_trunc(p0.x, p0.y); c[1] = pack_trunc(p0.z, p0.w);
      c[2] = pack_trunc(p1.x, p1.y); c[3] = pack_trunc(p1.z, p1.w);
      *(u32x4*)&sA[nxt][adst] = c;
    }
    __syncthreads();   // drains W DMA (vmcnt) + A ds_write (lgkmcnt)
  }

  // epilogue: hidden_proj reduce + bias, tanh, w_score, 16-lane reduce
  float hpv[4], wsv[4];
  #pragma unroll
  for (int ni = 0; ni < 4; ++ni) {
    const int col = n0 + wc*64 + ni*16 + lr;
    float h = bhid[col];
    #pragma unroll
    for (int z = 0; z < 4; ++z) h += hpp[z * 131072 + b * 512 + col];
    hpv[ni] = h;
    wsv[ni] = wsc[col];
  }
  const int p = blockIdx.y * 4 + wc;
  #pragma unroll
  for (int mi = 0; mi < 4; ++mi) {
    #pragma unroll
    for (int rr = 0; rr < 4; ++rr) {
      float s = 0.f;
      #pragma unroll
      for (int ni = 0; ni < 4; ++ni)
        s += fast_tanh(acc[mi][ni][rr] + hpv[ni]) * wsv[ni];
      s += __shfl_xor(s, 1, 64);
      s += __shfl_xor(s, 2, 64);
      s += __shfl_xor(s, 4, 64);
      s += __shfl_xor(s, 8, 64);
      if (lr == 0)
        epart[p * 65536 + m0 + wr*64 + mi*16 + kg*4 + rr] = s;
    }
  }
}

// ---------------- fused softmax + context (per batch element) ----------------
__global__ __launch_bounds__(256) void softctx_k(
    const float* __restrict__ epart, const float* __restrict__ H,
    float* __restrict__ alpha, u16* __restrict__ xh)
{
  const int bb = blockIdx.x, t = threadIdx.x;
  float e = 0.f;
  #pragma unroll
  for (int p = 0; p < 8; ++p) e += epart[p * 65536 + bb * 256 + t];
  float mx = e;
  #pragma unroll
  for (int o = 32; o >= 1; o >>= 1) mx = fmaxf(mx, __shfl_xor(mx, o, 64));
  __shared__ float sm[4], ss[4];
  if ((t & 63) == 0) sm[t >> 6] = mx;
  __syncthreads();
  mx = fmaxf(fmaxf(sm[0], sm[1]), fmaxf(sm[2], sm[3]));
  float ex = __expf(e - mx);
  float sum = ex;
  #pragma unroll
  for (int o = 32; o >= 1; o >>= 1) sum += __shfl_xor(sum, o, 64);
  if ((t & 63) == 0) ss[t >> 6] = sum;
  __syncthreads();
  sum = ss[0] + ss[1] + ss[2] + ss[3];
  const float av = ex / sum;
  alpha[bb * 256 + t] = av;
  __shared__ float sal[256];
  sal[t] = av;
  __syncthreads();
  const int q = t >> 6, c = t & 63;
  float a[8];
  #pragma unroll
  for (int j = 0; j < 8; ++j) a[j] = 0.f;
  const float* p = H + (size_t)bb * 131072 + c * 8;
  for (int s = q * 64; s < q * 64 + 64; ++s) {
    float4 v0 = *(const float4*)(p + (size_t)s * 512);
    float4 v1 = *(const float4*)(p + (size_t)s * 512 + 4);
    const float al = sal[s];
    a[0] = fmaf(al, v0.x, a[0]); a[1] = fmaf(al, v0.y, a[1]);
    a[2] = fmaf(al, v0.z, a[2]); a[3] = fmaf(al, v0.w, a[3]);
    a[4] = fmaf(al, v1.x, a[4]); a[5] = fmaf(al, v1.y, a[5]);
    a[6] = fmaf(al, v1.z, a[6]); a[7] = fmaf(al, v1.w, a[7]);
  }
  __shared__ float red[256][8];
  #pragma unroll
  for (int j = 0; j < 8; ++j) red[t][j] = a[j];
  __syncthreads();
  if (q == 0) {
    #pragma unroll
    for (int j = 0; j < 8; ++j) {
      float s = red[t][j] + red[t + 64][j] + red[t + 128][j] + red[t + 192][j];
      xh[bb * 1536 + c * 8 + j] = f2bf(s);
    }
  }
}

// ---------------- gates split-K reduce + bias + LSTM elementwise ----------------
__global__ __launch_bounds__(256) void lstm_reduce(
    const float* __restrict__ P, const float* __restrict__ biascat,
    const float* __restrict__ prev_c, float* __restrict__ out)
{
  const int idx = blockIdx.x * 256 + threadIdx.x;   // 0..131071
  const int b = idx >> 9, h = idx & 511;
  float gi = biascat[h], gf = biascat[512 + h], gg = biascat[1024 + h], go = biascat[1536 + h];
  #pragma unroll
  for (int z = 0; z < 4; ++z) {
    const float* q = P + (size_t)z * 524288 + (size_t)b * 2048;
    gi += q[h]; gf += q[512 + h]; gg += q[1024 + h]; go += q[1536 + h];
  }
  const float c = fast_sig(gf) * prev_c[idx] + fast_sig(gi) * fast_tanh(gg);
  out[idx] = fast_sig(go) * fast_tanh(c);   // h_new
  out[131072 + idx] = c;                     // c_new
}

extern "C" void kernel_launch(void* const* d_in, const int* in_sizes, int n_in,
                              void* d_out, int out_size, void* d_ws, size_t ws_size,
                              hipStream_t stream) {
  const float* prev_h  = (const float*)d_in[0];
  const float* prev_c  = (const float*)d_in[1];
  const float* batch_H = (const float*)d_in[2];
  const float* onehot  = (const float*)d_in[3];
  const float* W_feat  = (const float*)d_in[4];
  const float* W_hid   = (const float*)d_in[5];
  const float* b_hid   = (const float*)d_in[6];
  const float* w_score = (const float*)d_in[7];
  const float* W_ih    = (const float*)d_in[8];
  const float* W_hh    = (const float*)d_in[9];
  const float* b_ih    = (const float*)d_in[10];
  const float* b_hh    = (const float*)d_in[11];
  float* out = (float*)d_out;   // [h_new 131072 | c_new 131072 | alpha 65536]

  char* ws = (char*)d_ws;
  u16*   wfeat_b = (u16*)(ws);               //   524288 B
  u16*   whid_b  = (u16*)(ws + 524288);      //   524288 B
  u16*   wcat    = (u16*)(ws + 1048576);     //  6291456 B  [2048][1536] = [W_ih | W_hh]
  u16*   xh      = (u16*)(ws + 7340032);     //   786432 B  [256][1536] = [context|onehot|prev_h]
  float* biascat = (float*)(ws + 8126464);   //     8192 B
  float* hpp     = (float*)(ws + 8134656);   //  2097152 B  hidden partials [4][256][512]
  float* epart   = (float*)(ws + 10231808);  //  2097152 B  [8][65536]
  float* gpart   = (float*)(ws + 12328960);  //  8388608 B  gate partials [4][256][2048]
  // total 20717568 bytes

  float* alpha = out + 262144;

  prep_kernel<<<3842, 256, 0, stream>>>(W_feat, W_hid, W_ih, W_hh, onehot, prev_h,
                                        b_ih, b_hh, wfeat_b, whid_b, wcat, xh, biascat);
  // hidden_proj partials: prev_h @ W_hid^T  (split-K x4, bias folded into energies)
  gemm_btk<<<dim3(2, 4, 4), 256, 0, stream>>>(xh + 1024, 1536, whid_b, 512, 4, 131072, hpp, 512);
  // energies: fused feat_proj GEMM + hidden-reduce + tanh + w_score reduce (pipelined dbuf)
  energies_gemm<<<dim3(512, 2), 512, 0, stream>>>(batch_H, wfeat_b, hpp, b_hid, w_score, epart);
  // softmax + context (writes alpha output and xh context slice)
  softctx_k<<<256, 256, 0, stream>>>(epart, batch_H, alpha, xh);
  // gates partials: [context|onehot|prev_h] @ [W_ih|W_hh]^T (split-K x4)
  gemm_btk<<<dim3(2, 16, 4), 256, 0, stream>>>(xh, 1536, wcat, 1536, 12, 524288, gpart, 2048);
  // reduce + bias + LSTM
  lstm_reduce<<<512, 256, 0, stream>>>(gpart, biascat, prev_c, out);
}

// Round 6
// 118.553 us; speedup vs baseline: 1.3074x; 1.0728x over previous
//
#include <hip/hip_runtime.h>
#include <hip/hip_bf16.h>

typedef unsigned short u16;
typedef unsigned int u32;
typedef __attribute__((ext_vector_type(8))) short bf16x8;
typedef __attribute__((ext_vector_type(4))) float f32x4;
typedef __attribute__((ext_vector_type(4))) u32 u32x4;

typedef __attribute__((address_space(1))) const void gvoid;
typedef __attribute__((address_space(3))) void svoid;

__device__ __forceinline__ void gload16(const void* g, void* l) {
  __builtin_amdgcn_global_load_lds((gvoid*)g, (svoid*)l, 16, 0, 0);
}

__device__ __forceinline__ u16 f2bf(float x){
  union { float f; unsigned u; } v; v.f = x;
  unsigned r = v.u + 0x7fffu + ((v.u >> 16) & 1u);
  return (u16)(r >> 16);
}
// RNE pack of two f32 -> two bf16 in one instruction
__device__ __forceinline__ u32 cvtpk(float lo, float hi){
  u32 r;
  asm("v_cvt_pk_bf16_f32 %0, %1, %2" : "=v"(r) : "v"(lo), "v"(hi));
  return r;
}
__device__ __forceinline__ float fast_tanh(float x){
  x = fminf(fmaxf(x, -12.f), 12.f);
  float e = __expf(2.f * x);
  return (e - 1.f) / (e + 1.f);
}
__device__ __forceinline__ float fast_sig(float x){
  return 1.f / (1.f + __expf(-x));
}

// ---------------- prep: bf16 conversions + concat buffers (4 elems/thread) ----------------
__global__ __launch_bounds__(256) void prep_kernel(
    const float* __restrict__ Wfeat, const float* __restrict__ Whid,
    const float* __restrict__ Wih,   const float* __restrict__ Whh,
    const float* __restrict__ onehot,const float* __restrict__ prevh,
    const float* __restrict__ bih,   const float* __restrict__ bhh,
    u16* __restrict__ wfeat_b, u16* __restrict__ whid_b,
    u16* __restrict__ wcat, u16* __restrict__ xh, float* __restrict__ biascat)
{
  int idx = (blockIdx.x * 256 + threadIdx.x) * 4;
  const float* src;
  u16* dst;
  if (idx < 262144) { src = Wfeat + idx; dst = wfeat_b + idx; }
  else if ((idx -= 262144) < 262144) { src = Whid + idx; dst = whid_b + idx; }
  else if ((idx -= 262144) < 2097152) {
    int r = idx >> 10, k = idx & 1023; src = Wih + idx; dst = wcat + r*1536 + k;
  }
  else if ((idx -= 2097152) < 1048576) {
    int r = idx >> 9, k = idx & 511; src = Whh + idx; dst = wcat + r*1536 + 1024 + k;
  }
  else if ((idx -= 1048576) < 131072) {
    int b = idx >> 9, e = idx & 511; src = onehot + idx; dst = xh + b*1536 + 512 + e;
  }
  else if ((idx -= 131072) < 131072) {
    int b = idx >> 9, h = idx & 511; src = prevh + idx; dst = xh + b*1536 + 1024 + h;
  }
  else {
    idx -= 131072;
    if (idx < 2048) {
      float4 a = *(const float4*)(bih + idx);
      float4 b = *(const float4*)(bhh + idx);
      float4 c = { a.x + b.x, a.y + b.y, a.z + b.z, a.w + b.w };
      *(float4*)(biascat + idx) = c;
    }
    return;
  }
  float4 v = *(const float4*)src;
  ushort4 u;
  u.x = f2bf(v.x); u.y = f2bf(v.y); u.z = f2bf(v.z); u.w = f2bf(v.w);
  *(ushort4*)dst = u;
}

// ---------------- split-K partial GEMM: P[z] = A(bf16,[M][lda]) @ W(bf16,[N][ldw])^T ------
__global__ __launch_bounds__(256) void gemm_btk(
    const u16* __restrict__ Ab, int lda,
    const u16* __restrict__ Wb, int ldw,
    int ksteps, int pstride,
    float* __restrict__ P, int ldc)
{
  __shared__ u16 sA[128][40];
  __shared__ u16 sW[128][40];
  const int tid = threadIdx.x;
  const int lane = tid & 63, wave = tid >> 6;
  const int wr = wave >> 1, wc = wave & 1;
  const int lr = lane & 15, kg = lane >> 4;
  const int m0 = blockIdx.x * 128, n0 = blockIdx.y * 128;
  const int kbase = blockIdx.z * ksteps * 32;
  P += (size_t)blockIdx.z * pstride;
  const int sr = tid >> 1, sh = tid & 1;

  const f32x4 zero = {0.f, 0.f, 0.f, 0.f};
  f32x4 acc[4][4];
  #pragma unroll
  for (int i = 0; i < 4; ++i)
    #pragma unroll
    for (int j = 0; j < 4; ++j)
      acc[i][j] = zero;

  for (int ks = 0; ks < ksteps; ++ks) {
    const int kt = kbase + ks * 32;
    __syncthreads();
    {
      const u16* ap = Ab + (size_t)(m0 + sr) * lda + kt + sh * 16;
      *(bf16x8*)&sA[sr][sh*16]     = *(const bf16x8*)ap;
      *(bf16x8*)&sA[sr][sh*16 + 8] = *(const bf16x8*)(ap + 8);
      const u16* wp = Wb + (size_t)(n0 + sr) * ldw + kt + sh * 16;
      *(bf16x8*)&sW[sr][sh*16]     = *(const bf16x8*)wp;
      *(bf16x8*)&sW[sr][sh*16 + 8] = *(const bf16x8*)(wp + 8);
    }
    __syncthreads();
    bf16x8 af[4], wf[4];
    #pragma unroll
    for (int mi = 0; mi < 4; ++mi) af[mi] = *(const bf16x8*)&sA[wr*64 + mi*16 + lr][kg*8];
    #pragma unroll
    for (int ni = 0; ni < 4; ++ni) wf[ni] = *(const bf16x8*)&sW[wc*64 + ni*16 + lr][kg*8];
    #pragma unroll
    for (int mi = 0; mi < 4; ++mi)
      #pragma unroll
      for (int ni = 0; ni < 4; ++ni)
        acc[mi][ni] = __builtin_amdgcn_mfma_f32_16x16x32_bf16(af[mi], wf[ni], acc[mi][ni], 0, 0, 0);
  }

  #pragma unroll
  for (int ni = 0; ni < 4; ++ni) {
    const int col = n0 + wc*64 + ni*16 + lr;
    #pragma unroll
    for (int mi = 0; mi < 4; ++mi) {
      const int row = m0 + wr*64 + mi*16 + kg*4;
      #pragma unroll
      for (int rr = 0; rr < 4; ++rr)
        P[(size_t)(row + rr) * ldc + col] = acc[mi][ni][rr];
    }
  }
}

// ---------------- energies: counted-vmcnt pipelined GEMM, A = f32 (cvt_pk in-reg) --------
// A = batch_H f32 [65536][512], W = wfeat_b bf16 [512][512].
// BM=128, BN=256, BK=32; 512 threads, 8 waves (2x4), per-wave 64x64; grid (512,2).
// A prefetch: 2 tiles deep in registers (HBM latency); W: global_load_lds 1 deep (L2).
// Raw s_barrier + counted vmcnt(2): prefetched loads stay in flight across barriers.
__global__ __launch_bounds__(512, 4) void energies_gemm(
    const float* __restrict__ A, const u16* __restrict__ Wb,
    const float* __restrict__ hpp, const float* __restrict__ bhid,
    const float* __restrict__ wsc, float* __restrict__ epart)
{
  __shared__ u16 sA[2][128 * 32];   // 2 x 8 KB
  __shared__ u16 sW[2][256 * 32];   // 2 x 16 KB
  const int tid = threadIdx.x;
  const int lane = tid & 63, wv = tid >> 6;
  const int wr = wv >> 2, wc = wv & 3;
  const int lr = lane & 15, kg = lane >> 4;
  const int m0 = blockIdx.x * 128, n0 = blockIdx.y * 256;
  const int b = m0 >> 8;

  // A staging: thread -> (row = tid>>2, 8-f32 chunk = tid&3); swizzled dest chunk
  const int arow = tid >> 2, achk = tid & 3;
  const float* gA = A + (size_t)(m0 + arow) * 512 + achk * 8;
  const int adst = arow * 32 + ((achk ^ ((arow >> 1) & 3)) * 8);

  // W staging: 2 x gload16/thread; rows wv*16..+16 -> elems wv*512 (FIXED layout)
  const u16* gW0 = Wb + (size_t)(n0 + wv * 16 + (lane >> 2)) * 512 + (lane & 3) * 8;
  const u16* gW1 = gW0 + 128 * 512;
  const int wdst0 = wv * 512;
  const int wdst1 = wdst0 + 4096;

  const f32x4 zero = {0.f, 0.f, 0.f, 0.f};
  f32x4 acc[4][4];
  #pragma unroll
  for (int i = 0; i < 4; ++i)
    #pragma unroll
    for (int j = 0; j < 4; ++j)
      acc[i][j] = zero;

  float4 pa0, pa1, pb0, pb1;   // A reg sets: set0 = even tiles, set1 = odd tiles

  // prologue: W(0) -> sW[0]; A(0) -> set0; A(1) -> set1; convert A(0) -> sA[0]
  gload16(gW0, &sW[0][wdst0]);
  gload16(gW1, &sW[0][wdst1]);
  __builtin_amdgcn_sched_barrier(0);
  pa0 = *(const float4*)(gA);       pa1 = *(const float4*)(gA + 4);
  pb0 = *(const float4*)(gA + 32);  pb1 = *(const float4*)(gA + 36);
  __builtin_amdgcn_sched_barrier(0);
  {
    u32x4 c;
    c[0] = cvtpk(pa0.x, pa0.y); c[1] = cvtpk(pa0.z, pa0.w);
    c[2] = cvtpk(pa1.x, pa1.y); c[3] = cvtpk(pa1.z, pa1.w);
    *(u32x4*)&sA[0][adst] = c;   // compiler waits A(0); W(0) older -> also retired
  }
  asm volatile("s_waitcnt lgkmcnt(0)" ::: "memory");
  __builtin_amdgcn_s_barrier();
  __builtin_amdgcn_sched_barrier(0);

  #pragma unroll
  for (int t = 0; t < 16; ++t) {
    const int cur = t & 1, nxt = cur ^ 1;
    // phase 1: issue W(t+1) -> sW[nxt]
    if (t < 15) {
      const int kt = (t + 1) * 32;
      gload16(gW0 + kt, &sW[nxt][wdst0]);
      gload16(gW1 + kt, &sW[nxt][wdst1]);
    }
    __builtin_amdgcn_sched_barrier(0);
    // phase 2: issue A(t+2) -> reg set (t&1)
    if (t < 14) {
      const int kt = (t + 2) * 32;
      if (t & 1) { pb0 = *(const float4*)(gA + kt); pb1 = *(const float4*)(gA + kt + 4); }
      else       { pa0 = *(const float4*)(gA + kt); pa1 = *(const float4*)(gA + kt + 4); }
    }
    __builtin_amdgcn_sched_barrier(0);
    // phase 3: compute current buffer
    bf16x8 af[4], wf[4];
    #pragma unroll
    for (int mi = 0; mi < 4; ++mi) {
      const int row = wr*64 + mi*16 + lr;
      af[mi] = *(const bf16x8*)&sA[cur][row * 32 + ((kg ^ ((row >> 1) & 3)) * 8)];
    }
    #pragma unroll
    for (int ni = 0; ni < 4; ++ni)
      wf[ni] = *(const bf16x8*)&sW[cur][(wc*64 + ni*16 + lr) * 32 + kg*8];
    #pragma unroll
    for (int mi = 0; mi < 4; ++mi)
      #pragma unroll
      for (int ni = 0; ni < 4; ++ni)
        acc[mi][ni] = __builtin_amdgcn_mfma_f32_16x16x32_bf16(af[mi], wf[ni], acc[mi][ni], 0, 0, 0);
    // phase 4: convert A(t+1) (reg set (t+1)&1) -> sA[nxt]
    if (t < 15) {
      u32x4 c;
      if (t & 1) {  // A(t+1) is even -> set0
        c[0] = cvtpk(pa0.x, pa0.y); c[1] = cvtpk(pa0.z, pa0.w);
        c[2] = cvtpk(pa1.x, pa1.y); c[3] = cvtpk(pa1.z, pa1.w);
      } else {      // A(t+1) is odd -> set1
        c[0] = cvtpk(pb0.x, pb0.y); c[1] = cvtpk(pb0.z, pb0.w);
        c[2] = cvtpk(pb1.x, pb1.y); c[3] = cvtpk(pb1.z, pb1.w);
      }
      *(u32x4*)&sA[nxt][adst] = c;
    }
    // phase 5: boundary — wait W(t+1) landed (leave A(t+2) in flight), sync
    if (t < 15) {
      if (t < 14) asm volatile("s_waitcnt vmcnt(2)" ::: "memory");
      else        asm volatile("s_waitcnt vmcnt(0)" ::: "memory");
      asm volatile("s_waitcnt lgkmcnt(0)" ::: "memory");
      __builtin_amdgcn_s_barrier();
      __builtin_amdgcn_sched_barrier(0);
    }
  }

  // epilogue: hidden_proj reduce + bias, tanh, w_score, 16-lane reduce
  float hpv[4], wsv[4];
  #pragma unroll
  for (int ni = 0; ni < 4; ++ni) {
    const int col = n0 + wc*64 + ni*16 + lr;
    float h = bhid[col];
    #pragma unroll
    for (int z = 0; z < 4; ++z) h += hpp[z * 131072 + b * 512 + col];
    hpv[ni] = h;
    wsv[ni] = wsc[col];
  }
  const int p = blockIdx.y * 4 + wc;
  #pragma unroll
  for (int mi = 0; mi < 4; ++mi) {
    #pragma unroll
    for (int rr = 0; rr < 4; ++rr) {
      float s = 0.f;
      #pragma unroll
      for (int ni = 0; ni < 4; ++ni)
        s += fast_tanh(acc[mi][ni][rr] + hpv[ni]) * wsv[ni];
      s += __shfl_xor(s, 1, 64);
      s += __shfl_xor(s, 2, 64);
      s += __shfl_xor(s, 4, 64);
      s += __shfl_xor(s, 8, 64);
      if (lr == 0)
        epart[p * 65536 + m0 + wr*64 + mi*16 + kg*4 + rr] = s;
    }
  }
}

// ---------------- fused softmax + context (per batch element) ----------------
__global__ __launch_bounds__(256) void softctx_k(
    const float* __restrict__ epart, const float* __restrict__ H,
    float* __restrict__ alpha, u16* __restrict__ xh)
{
  const int bb = blockIdx.x, t = threadIdx.x;
  float e = 0.f;
  #pragma unroll
  for (int p = 0; p < 8; ++p) e += epart[p * 65536 + bb * 256 + t];
  float mx = e;
  #pragma unroll
  for (int o = 32; o >= 1; o >>= 1) mx = fmaxf(mx, __shfl_xor(mx, o, 64));
  __shared__ float sm[4], ss[4];
  if ((t & 63) == 0) sm[t >> 6] = mx;
  __syncthreads();
  mx = fmaxf(fmaxf(sm[0], sm[1]), fmaxf(sm[2], sm[3]));
  float ex = __expf(e - mx);
  float sum = ex;
  #pragma unroll
  for (int o = 32; o >= 1; o >>= 1) sum += __shfl_xor(sum, o, 64);
  if ((t & 63) == 0) ss[t >> 6] = sum;
  __syncthreads();
  sum = ss[0] + ss[1] + ss[2] + ss[3];
  const float av = ex / sum;
  alpha[bb * 256 + t] = av;
  __shared__ float sal[256];
  sal[t] = av;
  __syncthreads();
  const int q = t >> 6, c = t & 63;
  float a[8];
  #pragma unroll
  for (int j = 0; j < 8; ++j) a[j] = 0.f;
  const float* p = H + (size_t)bb * 131072 + c * 8;
  for (int s = q * 64; s < q * 64 + 64; ++s) {
    float4 v0 = *(const float4*)(p + (size_t)s * 512);
    float4 v1 = *(const float4*)(p + (size_t)s * 512 + 4);
    const float al = sal[s];
    a[0] = fmaf(al, v0.x, a[0]); a[1] = fmaf(al, v0.y, a[1]);
    a[2] = fmaf(al, v0.z, a[2]); a[3] = fmaf(al, v0.w, a[3]);
    a[4] = fmaf(al, v1.x, a[4]); a[5] = fmaf(al, v1.y, a[5]);
    a[6] = fmaf(al, v1.z, a[6]); a[7] = fmaf(al, v1.w, a[7]);
  }
  __shared__ float red[256][8];
  #pragma unroll
  for (int j = 0; j < 8; ++j) red[t][j] = a[j];
  __syncthreads();
  if (q == 0) {
    #pragma unroll
    for (int j = 0; j < 8; ++j) {
      float s = red[t][j] + red[t + 64][j] + red[t + 128][j] + red[t + 192][j];
      xh[bb * 1536 + c * 8 + j] = f2bf(s);
    }
  }
}

// ---------------- gates split-K reduce + bias + LSTM elementwise ----------------
__global__ __launch_bounds__(256) void lstm_reduce(
    const float* __restrict__ P, const float* __restrict__ biascat,
    const float* __restrict__ prev_c, float* __restrict__ out)
{
  const int idx = blockIdx.x * 256 + threadIdx.x;   // 0..131071
  const int b = idx >> 9, h = idx & 511;
  float gi = biascat[h], gf = biascat[512 + h], gg = biascat[1024 + h], go = biascat[1536 + h];
  #pragma unroll
  for (int z = 0; z < 4; ++z) {
    const float* q = P + (size_t)z * 524288 + (size_t)b * 2048;
    gi += q[h]; gf += q[512 + h]; gg += q[1024 + h]; go += q[1536 + h];
  }
  const float c = fast_sig(gf) * prev_c[idx] + fast_sig(gi) * fast_tanh(gg);
  out[idx] = fast_sig(go) * fast_tanh(c);   // h_new
  out[131072 + idx] = c;                     // c_new
}

extern "C" void kernel_launch(void* const* d_in, const int* in_sizes, int n_in,
                              void* d_out, int out_size, void* d_ws, size_t ws_size,
                              hipStream_t stream) {
  const float* prev_h  = (const float*)d_in[0];
  const float* prev_c  = (const float*)d_in[1];
  const float* batch_H = (const float*)d_in[2];
  const float* onehot  = (const float*)d_in[3];
  const float* W_feat  = (const float*)d_in[4];
  const float* W_hid   = (const float*)d_in[5];
  const float* b_hid   = (const float*)d_in[6];
  const float* w_score = (const float*)d_in[7];
  const float* W_ih    = (const float*)d_in[8];
  const float* W_hh    = (const float*)d_in[9];
  const float* b_ih    = (const float*)d_in[10];
  const float* b_hh    = (const float*)d_in[11];
  float* out = (float*)d_out;   // [h_new 131072 | c_new 131072 | alpha 65536]

  char* ws = (char*)d_ws;
  u16*   wfeat_b = (u16*)(ws);               //   524288 B
  u16*   whid_b  = (u16*)(ws + 524288);      //   524288 B
  u16*   wcat    = (u16*)(ws + 1048576);     //  6291456 B  [2048][1536] = [W_ih | W_hh]
  u16*   xh      = (u16*)(ws + 7340032);     //   786432 B  [256][1536] = [context|onehot|prev_h]
  float* biascat = (float*)(ws + 8126464);   //     8192 B
  float* hpp     = (float*)(ws + 8134656);   //  2097152 B  hidden partials [4][256][512]
  float* epart   = (float*)(ws + 10231808);  //  2097152 B  [8][65536]
  float* gpart   = (float*)(ws + 12328960);  //  8388608 B  gate partials [4][256][2048]
  // total 20717568 bytes

  float* alpha = out + 262144;

  prep_kernel<<<3842, 256, 0, stream>>>(W_feat, W_hid, W_ih, W_hh, onehot, prev_h,
                                        b_ih, b_hh, wfeat_b, whid_b, wcat, xh, biascat);
  // hidden_proj partials: prev_h @ W_hid^T  (split-K x4, bias folded into energies)
  gemm_btk<<<dim3(2, 4, 4), 256, 0, stream>>>(xh + 1024, 1536, whid_b, 512, 4, 131072, hpp, 512);
  // energies: fused feat_proj GEMM + hidden-reduce + tanh + w_score reduce (T4 pipeline)
  energies_gemm<<<dim3(512, 2), 512, 0, stream>>>(batch_H, wfeat_b, hpp, b_hid, w_score, epart);
  // softmax + context (writes alpha output and xh context slice)
  softctx_k<<<256, 256, 0, stream>>>(epart, batch_H, alpha, xh);
  // gates partials: [context|onehot|prev_h] @ [W_ih|W_hh]^T (split-K x4)
  gemm_btk<<<dim3(2, 16, 4), 256, 0, stream>>>(xh, 1536, wcat, 1536, 12, 524288, gpart, 2048);
  // reduce + bias + LSTM
  lstm_reduce<<<512, 256, 0, stream>>>(gpart, biascat, prev_c, out);
}